// Round 10
// baseline (215.929 us; speedup 1.0000x reference)
//
#include <hip/hip_runtime.h>

#define N_NODES 50000
#define NCH 256          // edge chunks (blocks in count/scatter)
#define NBKT 256         // bucket slots (dst>>8; 196 live for N=50000)

typedef short bf16x8 __attribute__((ext_vector_type(8)));
typedef float f32x4 __attribute__((ext_vector_type(4)));

__device__ inline unsigned short f2bf(float f) {
    union { float f; unsigned u; } v; v.f = f;
    unsigned u = v.u;
    unsigned lsb = (u >> 16) & 1u;
    u += 0x7fffu + lsb;  // round-to-nearest-even
    return (unsigned short)(u >> 16);
}

__device__ inline float bf2f(unsigned short h) {
    union { unsigned u; float f; } v; v.u = ((unsigned)h) << 16;
    return v.f;
}

// ============ prep: zero done-ctr + bucket histogram + W split ============
__global__ __launch_bounds__(256) void prep(const int* __restrict__ dst,
                                            int* __restrict__ cnt, int E, int epc,
                                            const float* __restrict__ W1,
                                            const float* __restrict__ W2,
                                            unsigned short* __restrict__ B1h,
                                            unsigned short* __restrict__ B1l,
                                            unsigned short* __restrict__ B2h,
                                            unsigned short* __restrict__ B2l,
                                            int* __restrict__ done) {
    const int c = blockIdx.x;
    if (c == 0 && threadIdx.x == 0) *done = 0;
    if (c < NCH) {
        __shared__ int h[NBKT];
        h[threadIdx.x] = 0;
        __syncthreads();
        const int e0 = c * epc;
        const int e1 = min(E, e0 + epc);
        for (int e = e0 + threadIdx.x; e < e1; e += 256)
            atomicAdd(&h[dst[e] >> 8], 1);
        __syncthreads();
        cnt[c * NBKT + threadIdx.x] = h[threadIdx.x];
        return;
    }
    // W split into MFMA fragment order:
    // Bf[((g*KS+ks)*64 + quad*16 + n16)*8 + j] = bf16(W^T[g*16+n16][ks*32+quad*8+j])
    int i = (c - NCH) * 256 + threadIdx.x;
    const float* W;
    unsigned short *Th, *Tl;
    int K, logM, idx;
    if (i < 32768) { W = W1; Th = B1h; Tl = B1l; K = 256; logM = 7; idx = i; }
    else if (i < 32768 + 8192) { W = W2; Th = B2h; Tl = B2l; K = 128; logM = 6; idx = i - 32768; }
    else return;
    const int M = 1 << logM;
    const int KS = K / 32;
    int k = idx >> logM;
    int n = idx & (M - 1);
    float v = W[idx];
    unsigned short h = f2bf(v);
    unsigned short l = f2bf(v - bf2f(h));
    int g = n >> 4, n16 = n & 15, ks = k >> 5, quad = (k >> 3) & 3, j = k & 7;
    size_t o = ((size_t)((g * KS + ks) * 64 + quad * 16 + n16)) * 8 + j;
    Th[o] = h;
    Tl[o] = l;
}

// S1+S2 fused: per-bucket scan over chunks; last finishing block scans totals
__global__ __launch_bounds__(256) void bkt_scan(const int* __restrict__ cnt,
                                                int* __restrict__ off,
                                                int* __restrict__ total,
                                                int* __restrict__ bbase,
                                                int* __restrict__ rowptr,
                                                int* __restrict__ done,
                                                int N, int E) {
    __shared__ int sh[256];
    __shared__ int lastflag;
    const int b = blockIdx.x;
    const int t = threadIdx.x;
    int v = cnt[t * NBKT + b];
    sh[t] = v;
    __syncthreads();
    for (int o = 1; o < 256; o <<= 1) {
        int u = (t >= o) ? sh[t - o] : 0;
        __syncthreads();
        sh[t] += u;
        __syncthreads();
    }
    off[t * NBKT + b] = sh[t] - v;
    if (t == 255)
        __hip_atomic_store(&total[b], sh[255], __ATOMIC_RELAXED, __HIP_MEMORY_SCOPE_AGENT);
    __threadfence();
    if (t == 0) {
        int old = __hip_atomic_fetch_add(done, 1, __ATOMIC_ACQ_REL, __HIP_MEMORY_SCOPE_AGENT);
        lastflag = (old == NBKT - 1);
    }
    __syncthreads();
    if (!lastflag) return;
    // this is the last block: scan totals -> bbase
    int tv = __hip_atomic_load(&total[t], __ATOMIC_RELAXED, __HIP_MEMORY_SCOPE_AGENT);
    sh[t] = tv;
    __syncthreads();
    for (int o = 1; o < 256; o <<= 1) {
        int u = (t >= o) ? sh[t - o] : 0;
        __syncthreads();
        sh[t] += u;
        __syncthreads();
    }
    bbase[t] = sh[t] - tv;
    if (t == 255) bbase[256] = sh[255];
    if (t == 0) rowptr[N] = E;
}

// B2: scatter packed (src<<8 | dst&255) into bucket-sorted order; LDS cursors
__global__ __launch_bounds__(256) void bkt_scatter(const int* __restrict__ src,
                                                   const int* __restrict__ dst,
                                                   const int* __restrict__ off,
                                                   const int* __restrict__ bbase,
                                                   unsigned* __restrict__ pairs,
                                                   int E, int epc) {
    __shared__ int cur[NBKT];
    const int c = blockIdx.x;
    cur[threadIdx.x] = bbase[threadIdx.x] + off[c * NBKT + threadIdx.x];
    __syncthreads();
    const int e0 = c * epc;
    const int e1 = min(E, e0 + epc);
    for (int e = e0 + threadIdx.x; e < e1; e += 256) {
        int s = src[e];
        int d = dst[e];
        int pos = atomicAdd(&cur[d >> 8], 1);
        pairs[pos] = ((unsigned)s << 8) | (unsigned)(d & 255);
    }
}

// B3: per-bucket local CSR: rowptr, dinv, csr_src (dense regional writes)
__global__ __launch_bounds__(256) void bkt_csr(const unsigned* __restrict__ pairs,
                                               const int* __restrict__ bbase,
                                               int* __restrict__ rowptr,
                                               int* __restrict__ csr_src,
                                               float* __restrict__ dinv, int N) {
    __shared__ int lh[256];
    __shared__ int sc[256];
    __shared__ int lcur[256];
    const int b = blockIdx.x;
    const int t = threadIdx.x;
    const int ebase = bbase[b];
    const int eend = bbase[b + 1];
    const int node0 = b << 8;

    lh[t] = 0;
    __syncthreads();
    for (int e = ebase + t; e < eend; e += 256)
        atomicAdd(&lh[pairs[e] & 255u], 1);
    __syncthreads();
    int v = lh[t];
    sc[t] = v;
    __syncthreads();
    for (int o = 1; o < 256; o <<= 1) {
        int u = (t >= o) ? sc[t - o] : 0;
        __syncthreads();
        sc[t] += u;
        __syncthreads();
    }
    const int excl = sc[t] - v;
    lcur[t] = ebase + excl;
    const int node = node0 + t;
    if (node < N) {
        rowptr[node] = ebase + excl;
        dinv[node] = rsqrtf((float)(v + 1));  // +1 self-loop
    }
    __syncthreads();
    for (int e = ebase + t; e < eend; e += 256) {
        unsigned p = pairs[e];
        int pos = atomicAdd(&lcur[p & 255u], 1);
        csr_src[pos] = (int)(p >> 8);
    }
}

// ============ MFMA GEMM (layer1): fp32 A -> 3-term split, 32x32/wave,
//              rolling B, dbuf LDS, bf16 out ============
template <int K, int M>
__global__ __launch_bounds__(M * 4) void gemm_mfma_v4(const float* __restrict__ A,
                                                      const unsigned short* __restrict__ Bfh,
                                                      const unsigned short* __restrict__ Bfl,
                                                      const float* __restrict__ dinv,
                                                      unsigned short* __restrict__ Cb, int N) {
    const int KS = K / 32;
    const int THREADS = M * 4;
    const int CPT = 512 / THREADS;
    const int PL = 64 * 40;
    const int CPAIRS = M / 32;

    __shared__ __align__(16) unsigned short Ah[2 * PL];
    __shared__ __align__(16) unsigned short Al[2 * PL];

    const int tid = threadIdx.x;
    const int wave = tid >> 6;
    const int lane = tid & 63;
    const int n16 = lane & 15;
    const int quad = lane >> 4;
    const int cpair = wave & (CPAIRS - 1);
    const int rpair = wave / CPAIRS;
    const int row0 = blockIdx.x * 64;

    bf16x8 bh[2][2], bl[2][2];
    auto loadB = [&](int ks, int par) {
#pragma unroll
        for (int ct = 0; ct < 2; ct++) {
            const int g = cpair * 2 + ct;
            const size_t o = ((size_t)(g * KS + ks) * 64 + lane) * 8;
            bh[par][ct] = *(const bf16x8*)(Bfh + o);
            bl[par][ct] = *(const bf16x8*)(Bfl + o);
        }
    };
    loadB(0, 0);

    int srow[CPT], sc4[CPT];
    const float* aptr[CPT];
#pragma unroll
    for (int p = 0; p < CPT; p++) {
        int q = p * THREADS + tid;
        srow[p] = q >> 3;
        sc4[p] = q & 7;
        int grow = row0 + srow[p];
        if (grow >= N) grow = N - 1;
        aptr[p] = A + (size_t)grow * K + sc4[p] * 4;
    }

    float4 pre[CPT];
#pragma unroll
    for (int p = 0; p < CPT; p++) pre[p] = *(const float4*)(aptr[p]);

#pragma unroll
    for (int p = 0; p < CPT; p++) {
        ushort4 h4, l4;
        unsigned short* hp = (unsigned short*)&h4;
        unsigned short* lp = (unsigned short*)&l4;
        float av[4] = {pre[p].x, pre[p].y, pre[p].z, pre[p].w};
#pragma unroll
        for (int j = 0; j < 4; j++) {
            unsigned short h = f2bf(av[j]);
            hp[j] = h;
            lp[j] = f2bf(av[j] - bf2f(h));
        }
        *(ushort4*)(Ah + srow[p] * 40 + sc4[p] * 4) = h4;
        *(ushort4*)(Al + srow[p] * 40 + sc4[p] * 4) = l4;
    }
    if (KS > 1) {
#pragma unroll
        for (int p = 0; p < CPT; p++) pre[p] = *(const float4*)(aptr[p] + 32);
    }
    __syncthreads();

    f32x4 acc[2][2] = {};

#pragma unroll
    for (int ks = 0; ks < KS; ks++) {
        const int cur = ks & 1;
        if (ks + 1 < KS) loadB(ks + 1, cur ^ 1);
#pragma unroll
        for (int rt = 0; rt < 2; rt++) {
            const int ro = cur * PL + (rpair * 32 + rt * 16 + n16) * 40 + quad * 8;
            bf16x8 ah = *(const bf16x8*)(Ah + ro);
            bf16x8 al = *(const bf16x8*)(Al + ro);
#pragma unroll
            for (int ct = 0; ct < 2; ct++) {
                acc[rt][ct] = __builtin_amdgcn_mfma_f32_16x16x32_bf16(ah, bh[cur][ct], acc[rt][ct], 0, 0, 0);
                acc[rt][ct] = __builtin_amdgcn_mfma_f32_16x16x32_bf16(ah, bl[cur][ct], acc[rt][ct], 0, 0, 0);
                acc[rt][ct] = __builtin_amdgcn_mfma_f32_16x16x32_bf16(al, bh[cur][ct], acc[rt][ct], 0, 0, 0);
            }
        }
        if (ks + 1 < KS) {
            const int nxt = (cur ^ 1) * PL;
#pragma unroll
            for (int p = 0; p < CPT; p++) {
                ushort4 h4, l4;
                unsigned short* hp = (unsigned short*)&h4;
                unsigned short* lp = (unsigned short*)&l4;
                float av[4] = {pre[p].x, pre[p].y, pre[p].z, pre[p].w};
#pragma unroll
                for (int j = 0; j < 4; j++) {
                    unsigned short h = f2bf(av[j]);
                    hp[j] = h;
                    lp[j] = f2bf(av[j] - bf2f(h));
                }
                *(ushort4*)(Ah + nxt + srow[p] * 40 + sc4[p] * 4) = h4;
                *(ushort4*)(Al + nxt + srow[p] * 40 + sc4[p] * 4) = l4;
            }
            if (ks + 2 < KS) {
#pragma unroll
                for (int p = 0; p < CPT; p++)
                    pre[p] = *(const float4*)(aptr[p] + (ks + 2) * 32);
            }
        }
        __syncthreads();
    }

#pragma unroll
    for (int rt = 0; rt < 2; rt++) {
#pragma unroll
        for (int ct = 0; ct < 2; ct++) {
            const int col = cpair * 32 + ct * 16 + n16;
            const int rbase = row0 + rpair * 32 + rt * 16 + quad * 4;
#pragma unroll
            for (int r = 0; r < 4; r++) {
                int orow = rbase + r;
                if (orow < N) {
                    Cb[(size_t)orow * M + col] = f2bf(dinv[orow] * acc[rt][ct][r]);
                }
            }
        }
    }
}

// ============ FUSED: gather1 (hn1b -> h1 rows) + gemm2 (h1 @ W2) ============
// Block: 1024 threads = 64 nodes. Gather phase writes h1 rows (bf16, after
// dinv/bias/ReLU) straight into the GEMM A-tile LDS planes (4 K-steps x
// 64 rows x 32 cols, stride 40). One barrier, then staging-free K-loop.
__global__ __launch_bounds__(1024, 4) void gather_gemm2(
        const unsigned short* __restrict__ hn1b,   // N x 128 bf16
        const int* __restrict__ rowptr,
        const int* __restrict__ csr_src,
        const float* __restrict__ dinv,
        const float* __restrict__ bias1,
        const unsigned short* __restrict__ B2h,    // frag order K=128,M=64
        const unsigned short* __restrict__ B2l,
        unsigned short* __restrict__ hn2b, int N) {
    const int PL = 64 * 40;
    __shared__ __align__(16) unsigned short Ah[4 * PL];  // 20.5 KB

    const int tid = threadIdx.x;
    const int row0 = blockIdx.x * 64;

    // ---- gather phase: thread -> (node r = tid>>4, chunk j = tid&15) ----
    {
        const int r = tid >> 4;     // 0..63
        const int j = tid & 15;     // 8-col chunk
        int g = row0 + r;
        if (g >= N) g = N - 1;
        float acc[8];
        {
            bf16x8 v = *(const bf16x8*)(hn1b + (size_t)g * 128 + j * 8);  // self-loop
#pragma unroll
            for (int i = 0; i < 8; i++) acc[i] = bf2f((unsigned short)v[i]);
        }
        int e = rowptr[g];
        const int end = rowptr[g + 1];
        for (; e + 3 < end; e += 4) {
            int s0 = csr_src[e];
            int s1 = csr_src[e + 1];
            int s2 = csr_src[e + 2];
            int s3 = csr_src[e + 3];
            bf16x8 v0 = *(const bf16x8*)(hn1b + (size_t)s0 * 128 + j * 8);
            bf16x8 v1 = *(const bf16x8*)(hn1b + (size_t)s1 * 128 + j * 8);
            bf16x8 v2 = *(const bf16x8*)(hn1b + (size_t)s2 * 128 + j * 8);
            bf16x8 v3 = *(const bf16x8*)(hn1b + (size_t)s3 * 128 + j * 8);
#pragma unroll
            for (int i = 0; i < 8; i++) {
                acc[i] += (bf2f((unsigned short)v0[i]) + bf2f((unsigned short)v1[i])) +
                          (bf2f((unsigned short)v2[i]) + bf2f((unsigned short)v3[i]));
            }
        }
        for (; e < end; e++) {
            int s0 = csr_src[e];
            bf16x8 v0 = *(const bf16x8*)(hn1b + (size_t)s0 * 128 + j * 8);
#pragma unroll
            for (int i = 0; i < 8; i++) acc[i] += bf2f((unsigned short)v0[i]);
        }
        const float s = dinv[g];
        float4 bv0 = *(const float4*)(bias1 + j * 8);
        float4 bv1 = *(const float4*)(bias1 + j * 8 + 4);
        float bb[8] = {bv0.x, bv0.y, bv0.z, bv0.w, bv1.x, bv1.y, bv1.z, bv1.w};
        bf16x8 rr;
#pragma unroll
        for (int i = 0; i < 8; i++)
            rr[i] = (short)f2bf(fmaxf(s * acc[i] + bb[i], 0.0f));  // ReLU
        // plane = j>>2 (K-step), in-plane col offset = (j&3)*8
        *(bf16x8*)(Ah + (j >> 2) * PL + r * 40 + (j & 3) * 8) = rr;
    }
    __syncthreads();

    // ---- GEMM phase: 16 waves; wave -> (rt = wave>>2, ct = wave&3) ----
    const int wave = tid >> 6;
    const int lane = tid & 63;
    const int n16 = lane & 15;
    const int quad = lane >> 4;
    const int rt = wave >> 2;
    const int ct = wave & 3;

    bf16x8 bh[2], bl[2];
    {
        const size_t o0 = ((size_t)(ct * 4) * 64 + lane) * 8;
        bh[0] = *(const bf16x8*)(B2h + o0);
        bl[0] = *(const bf16x8*)(B2l + o0);
    }
    f32x4 acc = {};
#pragma unroll
    for (int ks = 0; ks < 4; ks++) {
        const int cur = ks & 1;
        if (ks + 1 < 4) {
            const size_t o = ((size_t)(ct * 4 + ks + 1) * 64 + lane) * 8;
            bh[cur ^ 1] = *(const bf16x8*)(B2h + o);
            bl[cur ^ 1] = *(const bf16x8*)(B2l + o);
        }
        bf16x8 ah = *(const bf16x8*)(Ah + ks * PL + (rt * 16 + n16) * 40 + quad * 8);
        acc = __builtin_amdgcn_mfma_f32_16x16x32_bf16(ah, bh[cur], acc, 0, 0, 0);
        acc = __builtin_amdgcn_mfma_f32_16x16x32_bf16(ah, bl[cur], acc, 0, 0, 0);
    }
    const int col = ct * 16 + n16;
    const int rbase = row0 + rt * 16 + quad * 4;
#pragma unroll
    for (int r = 0; r < 4; r++) {
        int orow = rbase + r;
        if (orow < N) hn2b[(size_t)orow * 64 + col] = f2bf(dinv[orow] * acc[r]);
    }
}

// ============ gather-aggregate (bf16 rows in) -> fp32 out (final) ============
template <int M>
__global__ __launch_bounds__(256) void gather_to_f32(const unsigned short* __restrict__ hnb,
                                                     const int* __restrict__ rowptr,
                                                     const int* __restrict__ csr_src,
                                                     const float* __restrict__ dinv,
                                                     const float* __restrict__ bias,
                                                     float* __restrict__ outp, int n) {
    const int MQ = M / 8;
    const int GPB = 256 / MQ;
    int g = blockIdx.x * GPB + threadIdx.x / MQ;
    int j = threadIdx.x % MQ;
    if (g >= n) return;

    float acc[8];
    {
        bf16x8 v = *(const bf16x8*)(hnb + (size_t)g * M + j * 8);  // self-loop
#pragma unroll
        for (int i = 0; i < 8; i++) acc[i] = bf2f((unsigned short)v[i]);
    }

    int e = rowptr[g];
    const int end = rowptr[g + 1];
    for (; e + 3 < end; e += 4) {
        int s0 = csr_src[e];
        int s1 = csr_src[e + 1];
        int s2 = csr_src[e + 2];
        int s3 = csr_src[e + 3];
        bf16x8 v0 = *(const bf16x8*)(hnb + (size_t)s0 * M + j * 8);
        bf16x8 v1 = *(const bf16x8*)(hnb + (size_t)s1 * M + j * 8);
        bf16x8 v2 = *(const bf16x8*)(hnb + (size_t)s2 * M + j * 8);
        bf16x8 v3 = *(const bf16x8*)(hnb + (size_t)s3 * M + j * 8);
#pragma unroll
        for (int i = 0; i < 8; i++) {
            acc[i] += (bf2f((unsigned short)v0[i]) + bf2f((unsigned short)v1[i])) +
                      (bf2f((unsigned short)v2[i]) + bf2f((unsigned short)v3[i]));
        }
    }
    for (; e < end; e++) {
        int s0 = csr_src[e];
        bf16x8 v0 = *(const bf16x8*)(hnb + (size_t)s0 * M + j * 8);
#pragma unroll
        for (int i = 0; i < 8; i++) acc[i] += bf2f((unsigned short)v0[i]);
    }

    const float s = dinv[g];
    float r[8];
#pragma unroll
    for (int i = 0; i < 8; i++) r[i] = s * acc[i] + bias[j * 8 + i];
    float* op = outp + (size_t)g * M + j * 8;
    *(float4*)(op) = make_float4(r[0], r[1], r[2], r[3]);
    *(float4*)(op + 4) = make_float4(r[4], r[5], r[6], r[7]);
}

extern "C" void kernel_launch(void* const* d_in, const int* in_sizes, int n_in,
                              void* d_out, int out_size, void* d_ws, size_t ws_size,
                              hipStream_t stream) {
    const float* x  = (const float*)d_in[0];
    const int*   ei = (const int*)d_in[1];
    const float* W1 = (const float*)d_in[2];
    const float* b1 = (const float*)d_in[3];
    const float* W2 = (const float*)d_in[4];
    const float* b2 = (const float*)d_in[5];

    const int N = N_NODES;
    const int E = in_sizes[1] / 2;
    const int* src = ei;
    const int* dst = ei + E;

    char* ws = (char*)d_ws;
    size_t off = 0;
    auto carve = [&](size_t bytes) {
        char* p = ws + off;
        off += (bytes + 255) & ~(size_t)255;
        return p;
    };
    int*      cnt     = (int*)     carve((size_t)NCH * NBKT * 4);
    int*      offm    = (int*)     carve((size_t)NCH * NBKT * 4);
    int*      total   = (int*)     carve((size_t)NBKT * 4);
    int*      bbase   = (int*)     carve((size_t)(NBKT + 1) * 4);
    int*      done    = (int*)     carve(256);
    unsigned* pairs   = (unsigned*)carve((size_t)E * 4);
    int*      rowptr  = (int*)     carve((size_t)(N + 1) * 4);
    int*      csr_src = (int*)     carve((size_t)E * 4);
    float*    dinv    = (float*)   carve((size_t)N * 4);
    unsigned short* W1th = (unsigned short*)carve((size_t)256 * 128 * 2);
    unsigned short* W1tl = (unsigned short*)carve((size_t)256 * 128 * 2);
    unsigned short* W2th = (unsigned short*)carve((size_t)128 * 64 * 2);
    unsigned short* W2tl = (unsigned short*)carve((size_t)128 * 64 * 2);
    unsigned short* hn1b = (unsigned short*)carve((size_t)N * 128 * 2);  // bf16
    unsigned short* hn2b = (unsigned short*)carve((size_t)N * 64 * 2);   // bf16

    const int epc = (E + NCH - 1) / NCH;
    const int nbk = (N + 255) >> 8;  // 196 live buckets

    // ---- CSR build + weight split (5 -> 4 launches) ----
    prep<<<NCH + 160, 256, 0, stream>>>(dst, cnt, E, epc, W1, W2, W1th, W1tl, W2th, W2tl, done);
    bkt_scan<<<NBKT, 256, 0, stream>>>(cnt, offm, total, bbase, rowptr, done, N, E);
    bkt_scatter<<<NCH, 256, 0, stream>>>(src, dst, offm, bbase, pairs, E, epc);
    bkt_csr<<<nbk, 256, 0, stream>>>(pairs, bbase, rowptr, csr_src, dinv, N);

    const int GB = (N + 63) / 64;  // 782 blocks

    // ---- layer 1 GEMM ----
    gemm_mfma_v4<256, 128><<<GB, 512, 0, stream>>>(x, W1th, W1tl, dinv, hn1b, N);

    // ---- fused gather1 + layer 2 GEMM ----
    gather_gemm2<<<GB, 1024, 0, stream>>>(hn1b, rowptr, csr_src, dinv, b1,
                                          W2th, W2tl, hn2b, N);

    // ---- final gather ----
    {
        const int GPB = 256 / (64 / 8);  // 32 nodes/block
        gather_to_f32<64><<<(N + GPB - 1) / GPB, 256, 0, stream>>>(
            hn2b, rowptr, csr_src, dinv, b2, (float*)d_out, N);
    }
}